// Round 8
// baseline (328.765 us; speedup 1.0000x reference)
//
#include <hip/hip_runtime.h>

#define NN 100000
#define NE 1600000
#define BN_EPS 1e-5f
#define NBKT 6250         // fine buckets of 16 nodes (g = dst>>4)
#define CB 392            // coarse buckets of 256 nodes (cb = dst>>8; 391 used)
#define SCAP 4864         // slab capacity per coarse bucket (mean 4096, +12 sigma)
#define CPAD 16           // cursor stride in ints (64B)
#define NBLKA 400         // scatter blocks (fused kernel, blockIdx < NBLKA)
#define NPREB 782         // pre_gemm blocks (fused kernel, blockIdx >= NBLKA)
#define EPA 4000          // edges per scatter block (400*4000 = NE)
#define FSTR 72           // LDS F-tile row stride in shorts (144B rows, 16B-aligned)
#define NFRAG 48          // packed weight fragments
#define PSTR 16           // BN-partial stride in floats (64B lines)

typedef short s8v __attribute__((ext_vector_type(8)));
typedef float f4v __attribute__((ext_vector_type(4)));
typedef float f2v __attribute__((ext_vector_type(2)));
typedef unsigned u4v __attribute__((ext_vector_type(4)));

__device__ __forceinline__ float bf2f(unsigned short u) {
  union { unsigned u; float f; } v; v.u = ((unsigned)u) << 16; return v.f;
}
__device__ __forceinline__ unsigned fbits(float f) {
  union { float f; unsigned u; } v; v.f = f; return v.u;
}
__device__ __forceinline__ float bcast(unsigned u) {
  union { unsigned u; float f; } v; v.u = u; return v.f;
}
// round-half-up bf16 (ties differ from RNE with prob 2^-16 — negligible)
__device__ __forceinline__ unsigned short f2bf(float f) {
  return (unsigned short)((fbits(f) + 0x8000u) >> 16);
}
__device__ __forceinline__ s8v ldfrag(const unsigned short* __restrict__ pack,
                                      int f, int lane) {
  return *(const s8v*)(pack + ((size_t)f * 64 + lane) * 8);
}
// prelu(x) = max(x, a*x) — exact for 0 <= a <= 1 (a == 0.25 here)
__device__ __forceinline__ float prelu_m(float x, float a) { return fmaxf(x, a * x); }

// h1 on one dword pair (2 bf16 elems of F and G); packed-f32 add/mul/max
// (v_pk_* on CDNA) + RNE pack via v_cvt_pk_bf16_f32
__device__ __forceinline__ unsigned h1pair(unsigned fd, unsigned gd, float al) {
  f2v fv = { bcast(fd << 16), bcast(fd & 0xFFFF0000u) };
  f2v gv = { bcast(gd << 16), bcast(gd & 0xFFFF0000u) };
  f2v s = fv + gv;
  f2v m = __builtin_elementwise_max(s, s * al);
  unsigned rr;
  asm("v_cvt_pk_bf16_f32 %0, %1, %2" : "=v"(rr) : "v"(m.x), "v"(m.y));
  return rr;
}

#define MFMA16(a, b, c) __builtin_amdgcn_mfma_f32_16x16x32_bf16((a), (b), (c), 0, 0, 0)

// ---------------------------------------------------------------------------
// Weight pack (one-shot) + BN-partial zeroing + cursor zeroing.
// frag map: 0..7 W1 top | 8..15 W1 bot | 16..23 W2 | 24..39 W3 | 40..47 W4
// ---------------------------------------------------------------------------
__global__ __launch_bounds__(256) void pack_kernel(
    const float* __restrict__ W1, const float* __restrict__ W2,
    const float* __restrict__ W3, const float* __restrict__ W4,
    unsigned short* __restrict__ pack, float* __restrict__ part,
    int* __restrict__ cursor)
{
  for (int i = threadIdx.x; i < 128 * PSTR; i += 256) part[i] = 0.f;
  for (int i = threadIdx.x; i < CB * CPAD; i += 256) cursor[i] = 0;
  for (int it = threadIdx.x; it < NFRAG * 64; it += 256) {
    const int f = it >> 6;
    const int lane = it & 63;
    const int q = lane >> 4, r = lane & 15;
    const float* src; int rowoff, fi;
    if (f < 8)       { src = W1; rowoff = 0;  fi = f; }
    else if (f < 16) { src = W1; rowoff = 64; fi = f - 8; }
    else if (f < 24) { src = W2; rowoff = 0;  fi = f - 16; }
    else if (f < 40) { src = W3; rowoff = 0;  fi = f - 24; }
    else             { src = W4; rowoff = 0;  fi = f - 40; }
    const int kk = fi >> 2, nt = fi & 3;
    unsigned short tmp[8];
#pragma unroll
    for (int j = 0; j < 8; ++j)
      tmp[j] = f2bf(src[(size_t)(rowoff + kk * 32 + q * 8 + j) * 64 + nt * 16 + r]);
    *(s8v*)(pack + ((size_t)f * 64 + lane) * 8) = *(const s8v*)tmp;
  }
}

// ---------------------------------------------------------------------------
// FUSED: edge scatter (blocks 0..NBLKA-1) || pre-GEMM (blocks NBLKA..).
// Scatter kept at 400 blocks (longer runs per bucket = mergeable writes);
// pre_gemm at 782 blocks (2 tiles/wave) for better latency hiding.
// ---------------------------------------------------------------------------
__global__ __launch_bounds__(256) void pre_scatter_kernel(
    const float* __restrict__ x, const unsigned short* __restrict__ pack,
    const float* __restrict__ b1,
    unsigned short* __restrict__ F, unsigned short* __restrict__ G,
    unsigned short* __restrict__ XB,
    const int* __restrict__ srcp, const int* __restrict__ dstp,
    int* __restrict__ cursor, int* __restrict__ ebufA)
{
  __shared__ int lh[CB];
  __shared__ int lbase[CB];

  if (blockIdx.x < NBLKA) {
    // ---- scatter phase ----
    const int t = threadIdx.x;
    for (int i = t; i < CB; i += 256) lh[i] = 0;
    __syncthreads();
    const int base = blockIdx.x * EPA;
    for (int o = t; o < EPA; o += 256)
      atomicAdd(&lh[dstp[base + o] >> 8], 1);
    __syncthreads();
    for (int i = t; i < CB; i += 256) {
      const int c = lh[i];
      lbase[i] = c ? atomicAdd(&cursor[i * CPAD], c) : 0;
      lh[i] = 0;
    }
    __syncthreads();
    for (int o = t; o < EPA; o += 256) {
      const int d = dstp[base + o];
      const int s = srcp[base + o];
      const int cb = d >> 8;
      const int p = atomicAdd(&lh[cb], 1);
      ebufA[(size_t)cb * SCAP + lbase[cb] + p] = (s << 9) | (d & 511);
    }
    return;
  }

  // ---- pre_gemm phase ----
  const int lane = threadIdx.x & 63;
  const int wv   = threadIdx.x >> 6;
  const int q    = lane >> 4;
  const int r    = lane & 15;
  const int nw   = NPREB * 4;
  const int wid  = (blockIdx.x - NBLKA) * 4 + wv;

  s8v Bt[2][4], Bb[2][4];
#pragma unroll
  for (int kk = 0; kk < 2; ++kk)
#pragma unroll
    for (int nt = 0; nt < 4; ++nt) {
      Bt[kk][nt] = ldfrag(pack, kk * 4 + nt, lane);
      Bb[kk][nt] = ldfrag(pack, 8 + kk * 4 + nt, lane);
    }
  float b1c[4];
#pragma unroll
  for (int nt = 0; nt < 4; ++nt) b1c[nt] = b1[nt * 16 + r];

  for (int t = wid; t < NN / 16; t += nw) {
    const int n = t * 16 + r;
    const f4v* xp = (const f4v*)(x + (size_t)n * 64);
    f4v x0 = xp[q * 2],     x1 = xp[q * 2 + 1];
    f4v x2 = xp[8 + q * 2], x3 = xp[8 + q * 2 + 1];
    s8v a0, a1v;
#pragma unroll
    for (int j = 0; j < 4; ++j) {
      a0[j]      = (short)f2bf(x0[j]);
      a0[4 + j]  = (short)f2bf(x1[j]);
      a1v[j]     = (short)f2bf(x2[j]);
      a1v[4 + j] = (short)f2bf(x3[j]);
    }
    *(s8v*)(XB + (size_t)n * 64 + q * 8)      = a0;
    *(s8v*)(XB + (size_t)n * 64 + 32 + q * 8) = a1v;

    f4v aF[4], aG[4];
#pragma unroll
    for (int nt = 0; nt < 4; ++nt) {
      f4v c = {0.f, 0.f, 0.f, 0.f};
      c = MFMA16(a0,  Bt[0][nt], c);
      c = MFMA16(a1v, Bt[1][nt], c);
      aF[nt] = c;
      f4v d = {0.f, 0.f, 0.f, 0.f};
      d = MFMA16(a0,  Bb[0][nt], d);
      d = MFMA16(a1v, Bb[1][nt], d);
      aG[nt] = d;
    }
#pragma unroll
    for (int nt = 0; nt < 4; ++nt)
#pragma unroll
      for (int rg = 0; rg < 4; ++rg) {
        const size_t idx = (size_t)(t * 16 + q * 4 + rg) * 64 + nt * 16 + r;
        F[idx] = f2bf(aF[nt][rg] + b1c[nt]);
        G[idx] = f2bf(aG[nt][rg]);
      }
  }
}

// ---------------------------------------------------------------------------
// Pass B: one block per coarse slab; counting-sort ~4.1K edges into 16 fine
// buckets; emits absolute offsets fofs2[cb][0..16] into slab-addressed ebuf.
// ---------------------------------------------------------------------------
__global__ __launch_bounds__(256) void sort_b_kernel(
    const int* __restrict__ ebufA, const int* __restrict__ cursor,
    int* __restrict__ fofs2, int* __restrict__ ebuf)
{
  __shared__ int lh[4][16];
  __shared__ int cur[16];
  const int cb = blockIdx.x;
  int cnt = cursor[cb * CPAD];
  cnt = cnt < SCAP ? cnt : SCAP;
  const int base = cb * SCAP;
  const int t = threadIdx.x;
  const int wv = t >> 6;
  if (t < 64) lh[t >> 4][t & 15] = 0;
  __syncthreads();
  for (int i = t; i < cnt; i += 256)
    atomicAdd(&lh[wv][(ebufA[base + i] >> 4) & 15], 1);
  __syncthreads();
  if (t == 0) {
    int run = base;
    for (int fb = 0; fb < 16; ++fb) {
      const int v = lh[0][fb] + lh[1][fb] + lh[2][fb] + lh[3][fb];
      cur[fb] = run;
      fofs2[cb * 17 + fb] = run;
      run += v;
    }
    fofs2[cb * 17 + 16] = run;
  }
  __syncthreads();
  for (int i = t; i < cnt; i += 256) {
    const int w = ebufA[base + i];
    const int p = atomicAdd(&cur[(w >> 4) & 15], 1);
    ebuf[p] = w;
  }
}

// ---------------------------------------------------------------------------
// Edge MLP + aggregation: one wave per 16-node fine bucket. RMW-free.
// In-register h2 (swapped MFMA + cvt_pk + permlane32/16), packed sA build,
// packed-f32 prelu, unclamped LOADW (slack masked; src clamped < NN).
// ---------------------------------------------------------------------------
__global__ __launch_bounds__(256) void edge_agg_kernel(
    const unsigned short* __restrict__ F, const unsigned short* __restrict__ G,
    const int* __restrict__ ebuf, const int* __restrict__ fofs2,
    const unsigned short* __restrict__ pack,
    const float* __restrict__ a1p,
    const float* __restrict__ b2, const float* __restrict__ a2p,
    unsigned short* __restrict__ aggb)
{
  const int lane = threadIdx.x & 63;
  const int wv   = threadIdx.x >> 6;
  const int q    = lane >> 4;
  const int r    = lane & 15;

  __shared__ __align__(16) unsigned short ftl[4][16 * FSTR];   // per-wave F tile
  __shared__ __align__(16) unsigned short dbf[4][32];          // per-wave dloc
  unsigned short* ft = ftl[wv];
  unsigned short* db = dbf[wv];

  const int g = blockIdx.x * 4 + wv;
  if (g >= NBKT) return;                      // no block barriers below: safe

  const int cb = g >> 4, fb = g & 15;
  const int start = fofs2[cb * 17 + fb];
  const int end   = fofs2[cb * 17 + fb + 1];
  const int nbase = g * 16;

  s8v W2T[2][4];
#pragma unroll
  for (int kk = 0; kk < 2; ++kk)
#pragma unroll
    for (int ot = 0; ot < 4; ++ot)
      W2T[kk][ot] = ldfrag(pack, 16 + kk * 4 + ot, lane);

  // bias for swapped MFMA: C[row=edge][col=feat] -> per-lane scalar per ot
  float b2c[4];
#pragma unroll
  for (int ot = 0; ot < 4; ++ot) b2c[ot] = b2[ot * 16 + r];

  // uniform scalars -> SGPR
  union { float f; int i; } ua1, ua2;
  ua1.f = a1p[0]; ua1.i = __builtin_amdgcn_readfirstlane(ua1.i);
  ua2.f = a2p[0]; ua2.i = __builtin_amdgcn_readfirstlane(ua2.i);
  const float al1 = ua1.f;
  const float al2 = ua2.f;

  // F tile: 16 rows x 64 -> LDS (coalesced 2KB read), wave-private (DS in-order)
#pragma unroll
  for (int jj = 0; jj < 2; ++jj) {
    const int idx = jj * 64 + lane;
    const int row = idx >> 3, c8 = (idx & 7) * 8;
    s8v v = *(const s8v*)(F + (size_t)(nbase + row) * 64 + c8);
    *(s8v*)(ft + row * FSTR + c8) = v;
  }

  f4v acc[4];
#pragma unroll
  for (int ftx = 0; ftx < 4; ++ftx) acc[ftx] = (f4v){0.f, 0.f, 0.f, 0.f};

#define LOADW(c0, W0, W1)                                            \
  { W0 = ebuf[(c0) + r]; W1 = ebuf[(c0) + 16 + r]; }
#define ISSUEG(W0, W1, GA0, GB0, GA1, GB1)                           \
  { unsigned s0 = ((unsigned)(W0)) >> 9, s1 = ((unsigned)(W1)) >> 9; \
    s0 = s0 < NN ? s0 : 0u; s1 = s1 < NN ? s1 : 0u;                  \
    GA0 = *(const u4v*)(G + (size_t)s0 * 64 + q * 8);                \
    GB0 = *(const u4v*)(G + (size_t)s0 * 64 + 32 + q * 8);           \
    GA1 = *(const u4v*)(G + (size_t)s1 * 64 + q * 8);                \
    GB1 = *(const u4v*)(G + (size_t)s1 * 64 + 32 + q * 8); }

  if (start < end) {
    int w0c, w1c, w0n, w1n;
    u4v ga0c, gb0c, ga1c, gb1c, ga0n, gb0n, ga1n, gb1n;
    LOADW(start, w0c, w1c);
    ISSUEG(w0c, w1c, ga0c, gb0c, ga1c, gb1c);
    LOADW(start + 32, w0n, w1n);

    for (int c0 = start; c0 < end; c0 += 32) {
      const int dl0 = w0c & 15, dl1 = w1c & 15;
      if (q == 0) {
        db[r]      = (unsigned short)((c0 + r < end) ? dl0 : 0xFF);
        db[16 + r] = (unsigned short)((c0 + 16 + r < end) ? dl1 : 0xFF);
      }
      // F rows from LDS tile
      u4v fa0 = *(const u4v*)(ft + dl0 * FSTR + q * 8);
      u4v fb0 = *(const u4v*)(ft + dl0 * FSTR + 32 + q * 8);
      u4v fa1 = *(const u4v*)(ft + dl1 * FSTR + q * 8);
      u4v fb1 = *(const u4v*)(ft + dl1 * FSTR + 32 + q * 8);

      union { u4v u; s8v s; } P00, P01, P10, P11;
#pragma unroll
      for (int j = 0; j < 4; ++j) {
        P00.u[j] = h1pair(fa0[j], ga0c[j], al1);
        P01.u[j] = h1pair(fb0[j], gb0c[j], al1);
        P10.u[j] = h1pair(fa1[j], ga1c[j], al1);
        P11.u[j] = h1pair(fb1[j], gb1c[j], al1);
      }

      // G registers consumed -> launch next chunk's gathers + future words
      ISSUEG(w0n, w1n, ga0n, gb0n, ga1n, gb1n);
      int w0f, w1f;
      LOADW(c0 + 64, w0f, w1f);

      // S^T indicator A-frag: A[m=node=r][k=edge=q*8+j], packed build:
      // per dword (2 dlocs): x = dv ^ (r|r<<16); halves are 0 iff match;
      // t = pk_sub_i16(pk_min_u16(x,1), 1) = 0xFFFF iff match; & bf16(1.0).
      u4v dvw = *(const u4v*)(db + q * 8);
      const unsigned rr = (unsigned)r * 0x00010001u;
      union { unsigned w[4]; s8v s; } sAu;
#pragma unroll
      for (int k = 0; k < 4; ++k) {
        unsigned x = dvw[k] ^ rr;
        unsigned m, t;
        asm("v_pk_min_u16 %0, %1, %2" : "=v"(m) : "v"(x), "s"(0x00010001u));
        asm("v_pk_sub_i16 %0, %1, %2" : "=v"(t) : "v"(m), "s"(0x00010001u));
        sAu.w[k] = t & 0x3F803F80u;
      }
      const s8v sA = sAu.s;

      // Swapped h2-MFMA: D[m=edge][n=feat]. Lane (q,r) holds edges
      // q*4+rg (c) and 16+q*4+rg (d) at feat ot*16+r. cvt_pk packs edge
      // pairs; permlane32+16 swaps turn quarters (A0,A1,A2,A3)x(B0..B3)
      // into (A0,A2,B0,B2) / (A1,A3,B1,B3) = agg B-frag dwords.
#pragma unroll
      for (int ot = 0; ot < 4; ++ot) {
        const float bb = b2c[ot];
        const f4v binit = {bb, bb, bb, bb};
        f4v c = binit;
        c = MFMA16(P00.s, W2T[0][ot], c);
        c = MFMA16(P01.s, W2T[1][ot], c);
        f4v d = binit;
        d = MFMA16(P10.s, W2T[0][ot], d);
        d = MFMA16(P11.s, W2T[1][ot], d);
        f4v cm = __builtin_elementwise_max(c, c * al2);
        f4v dm = __builtin_elementwise_max(d, d * al2);
        unsigned pc0, pc1, pd0, pd1;
        asm("v_cvt_pk_bf16_f32 %0, %1, %2" : "=v"(pc0) : "v"(cm.x), "v"(cm.y));
        asm("v_cvt_pk_bf16_f32 %0, %1, %2" : "=v"(pc1) : "v"(cm.z), "v"(cm.w));
        asm("v_cvt_pk_bf16_f32 %0, %1, %2" : "=v"(pd0) : "v"(dm.x), "v"(dm.y));
        asm("v_cvt_pk_bf16_f32 %0, %1, %2" : "=v"(pd1) : "v"(dm.z), "v"(dm.w));
        // (x,y) -> x=(x.lo,y.lo), y=(x.hi,y.hi)
        asm("v_permlane32_swap_b32 %0, %1" : "+v"(pc0), "+v"(pd0));
        // (x,y) -> x=(x.q0,y.q0,x.q2,y.q2), y=(x.q1,y.q1,x.q3,y.q3)
        asm("v_permlane16_swap_b32 %0, %1" : "+v"(pc0), "+v"(pd0));
        asm("v_permlane32_swap_b32 %0, %1" : "+v"(pc1), "+v"(pd1));
        asm("v_permlane16_swap_b32 %0, %1" : "+v"(pc1), "+v"(pd1));
        union { unsigned w[4]; s8v s; } Bf;
        Bf.w[0] = pc0;  // edges q*8+0,1
        Bf.w[1] = pc1;  // edges q*8+2,3
        Bf.w[2] = pd0;  // edges q*8+4,5
        Bf.w[3] = pd1;  // edges q*8+6,7
        acc[ot] = MFMA16(sA, Bf.s, acc[ot]);
      }

      // rotate pipeline
      w0c = w0n; w1c = w1n; w0n = w0f; w1n = w1f;
      ga0c = ga0n; gb0c = gb0n; ga1c = ga1n; gb1c = gb1n;
    }
  }
#undef LOADW
#undef ISSUEG

  // flush: one bf16 store per (node, feature)
#pragma unroll
  for (int ftx = 0; ftx < 4; ++ftx)
#pragma unroll
    for (int rg = 0; rg < 4; ++rg) {
      const int node = nbase + q * 4 + rg;
      aggb[(size_t)node * 64 + ftx * 16 + r] = f2bf(acc[ftx][rg]);
    }
}

// ---------------------------------------------------------------------------
// Node MLP: z = prelu(prelu(cat(x,agg) @ W3 + b3) @ W4 + b4, a_blk)
// BN partials go to line-strided part[f*PSTR].
// ---------------------------------------------------------------------------
__global__ __launch_bounds__(256) void node_mlp_kernel(
    const unsigned short* __restrict__ XB,
    const unsigned short* __restrict__ aggb,
    const unsigned short* __restrict__ pack,
    const float* __restrict__ b3, const float* __restrict__ a3p,
    const float* __restrict__ b4, const float* __restrict__ ablkp,
    unsigned short* __restrict__ zb,
    float* __restrict__ part)
{
  const int lane = threadIdx.x & 63;
  const int wv   = threadIdx.x >> 6;
  const int q    = lane >> 4;
  const int r    = lane & 15;
  const int nw   = gridDim.x * 4;
  const int wid  = blockIdx.x * 4 + wv;

  s8v B3f[4][4];
  s8v B4f[2][4];
#pragma unroll
  for (int kk = 0; kk < 4; ++kk)
#pragma unroll
    for (int nt = 0; nt < 4; ++nt)
      B3f[kk][nt] = ldfrag(pack, 24 + kk * 4 + nt, lane);
#pragma unroll
  for (int kk = 0; kk < 2; ++kk)
#pragma unroll
    for (int nt = 0; nt < 4; ++nt)
      B4f[kk][nt] = ldfrag(pack, 40 + kk * 4 + nt, lane);

  float bias3[4], bias4[4];
#pragma unroll
  for (int nt = 0; nt < 4; ++nt) { bias3[nt] = b3[nt * 16 + r]; bias4[nt] = b4[nt * 16 + r]; }
  const float al3 = a3p[0];
  const float alb = ablkp[0];

  __shared__ __align__(16) unsigned short hbuf[4][16 * 72];
  unsigned short* hb = hbuf[wv];

  float bs[4] = {0.f, 0.f, 0.f, 0.f};
  float bq[4] = {0.f, 0.f, 0.f, 0.f};

  for (int t = wid; t < NN / 16; t += nw) {
    const int n = t * 16 + r;
    const s8v* xn = (const s8v*)(XB + (size_t)n * 64);
    const s8v* an = (const s8v*)(aggb + (size_t)n * 64);
    s8v a0  = xn[q];
    s8v a1v = xn[q + 4];
    s8v a2v = an[q];
    s8v a3v = an[q + 4];

    f4v acc[4];
#pragma unroll
    for (int nt = 0; nt < 4; ++nt) {
      f4v c = {0.f, 0.f, 0.f, 0.f};
      c = MFMA16(a0,  B3f[0][nt], c);
      c = MFMA16(a1v, B3f[1][nt], c);
      c = MFMA16(a2v, B3f[2][nt], c);
      c = MFMA16(a3v, B3f[3][nt], c);
      acc[nt] = c;
    }

#pragma unroll
    for (int nt = 0; nt < 4; ++nt)
#pragma unroll
      for (int rg = 0; rg < 4; ++rg) {
        float v = prelu_m(acc[nt][rg] + bias3[nt], al3);
        hb[(q * 4 + rg) * 72 + nt * 16 + r] = f2bf(v);
      }
    s8v p0 = *(const s8v*)(hb + r * 72 + q * 8);
    s8v p1 = *(const s8v*)(hb + r * 72 + 32 + q * 8);

    f4v acc2[4];
#pragma unroll
    for (int nt = 0; nt < 4; ++nt) {
      f4v c = {0.f, 0.f, 0.f, 0.f};
      c = MFMA16(p0, B4f[0][nt], c);
      c = MFMA16(p1, B4f[1][nt], c);
      acc2[nt] = c;
    }

#pragma unroll
    for (int nt = 0; nt < 4; ++nt)
#pragma unroll
      for (int rg = 0; rg < 4; ++rg) {
        float v = prelu_m(acc2[nt][rg] + bias4[nt], alb);
        const int row = t * 16 + q * 4 + rg;
        zb[(size_t)row * 64 + nt * 16 + r] = f2bf(v);
        bs[nt] += v;
        bq[nt] += v * v;
      }
  }

#pragma unroll
  for (int nt = 0; nt < 4; ++nt) {
    float s = bs[nt];
    s += __shfl_xor(s, 16, 64);
    s += __shfl_xor(s, 32, 64);
    float ss = bq[nt];
    ss += __shfl_xor(ss, 16, 64);
    ss += __shfl_xor(ss, 32, 64);
    if (q == 0) {
      atomicAdd(&part[(nt * 16 + r) * PSTR], s);
      atomicAdd(&part[(64 + nt * 16 + r) * PSTR], ss);
    }
  }
}

// ---------------------------------------------------------------------------
// BatchNorm finalize: grid-stride stream; reads z (bf16) + strided partials
// ---------------------------------------------------------------------------
__global__ __launch_bounds__(256) void bn_kernel(
    const unsigned short* __restrict__ zb,
    float* __restrict__ out,
    const float* __restrict__ part,
    const float* __restrict__ gamma,
    const float* __restrict__ beta)
{
  const size_t total = (size_t)NN * 16;   // quads of 4 elems
  const float inv_n = 1.0f / (float)NN;
  for (size_t i = (size_t)blockIdx.x * 256 + threadIdx.x; i < total;
       i += (size_t)gridDim.x * 256) {
    ushort4 v = ((const ushort4*)zb)[i];
    unsigned short e[4] = {v.x, v.y, v.z, v.w};
    float o[4];
    const int f0 = (int)((i * 4) & 63);
#pragma unroll
    for (int j = 0; j < 4; ++j) {
      const int f = f0 + j;
      const float mean = part[f * PSTR] * inv_n;
      const float var  = part[(64 + f) * PSTR] * inv_n - mean * mean;
      const float sc = rsqrtf(var + BN_EPS) * gamma[f];
      const float sh = beta[f] - mean * sc;
      o[j] = bf2f(e[j]) * sc + sh;
    }
    ((float4*)out)[i] = make_float4(o[0], o[1], o[2], o[3]);
  }
}

extern "C" void kernel_launch(void* const* d_in, const int* in_sizes, int n_in,
                              void* d_out, int out_size, void* d_ws, size_t ws_size,
                              hipStream_t stream) {
  const float* x  = (const float*)d_in[0];
  const int* ei   = (const int*)d_in[1];
  const float* W1 = (const float*)d_in[2];
  const float* b1 = (const float*)d_in[3];
  const float* a1 = (const float*)d_in[4];
  const float* W2 = (const float*)d_in[5];
  const float* b2 = (const float*)d_in[6];
  const float* a2 = (const float*)d_in[7];
  const float* W3 = (const float*)d_in[8];
  const float* b3 = (const float*)d_in[9];
  const float* a3 = (const float*)d_in[10];
  const float* W4 = (const float*)d_in[11];
  const float* b4 = (const float*)d_in[12];
  const float* ab = (const float*)d_in[13];
  const float* gm = (const float*)d_in[14];
  const float* bt = (const float*)d_in[15];

  float* part          = (float*)d_ws;                    // [128*PSTR] f32
  unsigned short* aggb = (unsigned short*)(part + 128 * PSTR);  // [NN*64] bf16
  unsigned short* F    = aggb + (size_t)NN * 64;          // [NN*64] bf16 (+b1)
  unsigned short* G    = F + (size_t)NN * 64;             // [NN*64] bf16
  unsigned short* XB   = G + (size_t)NN * 64;             // [NN*64] bf16
  unsigned short* zb   = XB + (size_t)NN * 64;            // [NN*64] bf16
  int* cursor          = (int*)(zb + (size_t)NN * 64);    // [CB*CPAD] padded
  int* fofs2           = cursor + (size_t)CB * CPAD;      // [CB*17] (+pad)
  int* ebufA           = fofs2 + CB * 17 + 8;             // [CB*SCAP]
  int* ebuf            = ebufA + (size_t)CB * SCAP;       // [CB*SCAP + 128]
  unsigned short* pack = (unsigned short*)(ebuf + (size_t)CB * SCAP + 128);
  float* out           = (float*)d_out;

  const int* srcp = ei;        // edge_index[0] = src (x_j)
  const int* dstp = ei + NE;   // edge_index[1] = dst (x_i)

  pack_kernel<<<dim3(1), dim3(256), 0, stream>>>(W1, W2, W3, W4, pack, part, cursor);
  pre_scatter_kernel<<<dim3(NBLKA + NPREB), dim3(256), 0, stream>>>(
      x, pack, b1, F, G, XB, srcp, dstp, cursor, ebufA);
  sort_b_kernel<<<dim3(CB), dim3(256), 0, stream>>>(ebufA, cursor, fofs2, ebuf);
  edge_agg_kernel<<<dim3((NBKT + 3) / 4), dim3(256), 0, stream>>>(
      F, G, ebuf, fofs2, pack, a1, b2, a2, aggb);
  node_mlp_kernel<<<dim3(782), dim3(256), 0, stream>>>(
      XB, aggb, pack, b3, a3, b4, ab, zb, part);
  bn_kernel<<<dim3(2048), dim3(256), 0, stream>>>(zb, out, part, gm, bt);
}

// Round 9
// 234.126 us; speedup vs baseline: 1.4042x; 1.4042x over previous
//
#include <hip/hip_runtime.h>

#define NN 100000
#define NE 1600000
#define BN_EPS 1e-5f
#define NBKT 6250         // fine buckets of 16 nodes (g = dst>>4)
#define CB 392            // coarse buckets of 256 nodes (cb = dst>>8; 391 used)
#define SCAP 4864         // slab capacity per coarse bucket (mean 4096, +12 sigma)
#define CPAD 16           // cursor stride in ints (64B)
#define NBLKA 400         // scatter blocks (fused kernel, blockIdx < NBLKA)
#define NPREB 391         // pre_gemm blocks (fused kernel, blockIdx >= NBLKA)
#define EPA 4000          // edges per scatter block (400*4000 = NE)
#define FSTR 72           // LDS F-tile row stride in shorts (144B rows, 16B-aligned)
#define NFRAG 48          // packed weight fragments

typedef short s8v __attribute__((ext_vector_type(8)));
typedef float f4v __attribute__((ext_vector_type(4)));
typedef float f2v __attribute__((ext_vector_type(2)));
typedef unsigned u4v __attribute__((ext_vector_type(4)));

__device__ __forceinline__ float bf2f(unsigned short u) {
  union { unsigned u; float f; } v; v.u = ((unsigned)u) << 16; return v.f;
}
__device__ __forceinline__ unsigned fbits(float f) {
  union { float f; unsigned u; } v; v.f = f; return v.u;
}
__device__ __forceinline__ float bcast(unsigned u) {
  union { unsigned u; float f; } v; v.u = u; return v.f;
}
// round-half-up bf16 (ties differ from RNE with prob 2^-16 — negligible)
__device__ __forceinline__ unsigned short f2bf(float f) {
  return (unsigned short)((fbits(f) + 0x8000u) >> 16);
}
__device__ __forceinline__ s8v ldfrag(const unsigned short* __restrict__ pack,
                                      int f, int lane) {
  return *(const s8v*)(pack + ((size_t)f * 64 + lane) * 8);
}
// prelu(x) = max(x, a*x) — exact for 0 <= a <= 1 (a == 0.25 here)
__device__ __forceinline__ float prelu_m(float x, float a) { return fmaxf(x, a * x); }

// h1 on one dword pair (2 bf16 elems of F and G); packed-f32 add/mul/max
// + RNE pack via v_cvt_pk_bf16_f32
__device__ __forceinline__ unsigned h1pair(unsigned fd, unsigned gd, float al) {
  f2v fv = { bcast(fd << 16), bcast(fd & 0xFFFF0000u) };
  f2v gv = { bcast(gd << 16), bcast(gd & 0xFFFF0000u) };
  f2v s = fv + gv;
  f2v m = __builtin_elementwise_max(s, s * al);
  unsigned rr;
  asm("v_cvt_pk_bf16_f32 %0, %1, %2" : "=v"(rr) : "v"(m.x), "v"(m.y));
  return rr;
}

#define MFMA16(a, b, c) __builtin_amdgcn_mfma_f32_16x16x32_bf16((a), (b), (c), 0, 0, 0)

// ---------------------------------------------------------------------------
// Weight pack (one-shot) + BN-partial zeroing + cursor zeroing.
// frag map: 0..7 W1 top | 8..15 W1 bot | 16..23 W2 | 24..39 W3 | 40..47 W4
// ---------------------------------------------------------------------------
__global__ __launch_bounds__(256) void pack_kernel(
    const float* __restrict__ W1, const float* __restrict__ W2,
    const float* __restrict__ W3, const float* __restrict__ W4,
    unsigned short* __restrict__ pack, float* __restrict__ part,
    int* __restrict__ cursor)
{
  if (threadIdx.x < 128) part[threadIdx.x] = 0.f;
  for (int i = threadIdx.x; i < CB * CPAD; i += 256) cursor[i] = 0;
  for (int it = threadIdx.x; it < NFRAG * 64; it += 256) {
    const int f = it >> 6;
    const int lane = it & 63;
    const int q = lane >> 4, r = lane & 15;
    const float* src; int rowoff, fi;
    if (f < 8)       { src = W1; rowoff = 0;  fi = f; }
    else if (f < 16) { src = W1; rowoff = 64; fi = f - 8; }
    else if (f < 24) { src = W2; rowoff = 0;  fi = f - 16; }
    else if (f < 40) { src = W3; rowoff = 0;  fi = f - 24; }
    else             { src = W4; rowoff = 0;  fi = f - 40; }
    const int kk = fi >> 2, nt = fi & 3;
    unsigned short tmp[8];
#pragma unroll
    for (int j = 0; j < 8; ++j)
      tmp[j] = f2bf(src[(size_t)(rowoff + kk * 32 + q * 8 + j) * 64 + nt * 16 + r]);
    *(s8v*)(pack + ((size_t)f * 64 + lane) * 8) = *(const s8v*)tmp;
  }
}

// ---------------------------------------------------------------------------
// FUSED: edge scatter (blocks 0..NBLKA-1) || pre-GEMM (blocks NBLKA..).
// ---------------------------------------------------------------------------
__global__ __launch_bounds__(256) void pre_scatter_kernel(
    const float* __restrict__ x, const unsigned short* __restrict__ pack,
    const float* __restrict__ b1,
    unsigned short* __restrict__ F, unsigned short* __restrict__ G,
    unsigned short* __restrict__ XB,
    const int* __restrict__ srcp, const int* __restrict__ dstp,
    int* __restrict__ cursor, int* __restrict__ ebufA)
{
  __shared__ int lh[CB];
  __shared__ int lbase[CB];

  if (blockIdx.x < NBLKA) {
    // ---- scatter phase ----
    const int t = threadIdx.x;
    for (int i = t; i < CB; i += 256) lh[i] = 0;
    __syncthreads();
    const int base = blockIdx.x * EPA;
    for (int o = t; o < EPA; o += 256)
      atomicAdd(&lh[dstp[base + o] >> 8], 1);
    __syncthreads();
    for (int i = t; i < CB; i += 256) {
      const int c = lh[i];
      lbase[i] = c ? atomicAdd(&cursor[i * CPAD], c) : 0;
      lh[i] = 0;
    }
    __syncthreads();
    for (int o = t; o < EPA; o += 256) {
      const int d = dstp[base + o];
      const int s = srcp[base + o];
      const int cb = d >> 8;
      const int p = atomicAdd(&lh[cb], 1);
      ebufA[(size_t)cb * SCAP + lbase[cb] + p] = (s << 9) | (d & 511);
    }
    return;
  }

  // ---- pre_gemm phase ----
  const int lane = threadIdx.x & 63;
  const int wv   = threadIdx.x >> 6;
  const int q    = lane >> 4;
  const int r    = lane & 15;
  const int nw   = NPREB * 4;
  const int wid  = (blockIdx.x - NBLKA) * 4 + wv;

  s8v Bt[2][4], Bb[2][4];
#pragma unroll
  for (int kk = 0; kk < 2; ++kk)
#pragma unroll
    for (int nt = 0; nt < 4; ++nt) {
      Bt[kk][nt] = ldfrag(pack, kk * 4 + nt, lane);
      Bb[kk][nt] = ldfrag(pack, 8 + kk * 4 + nt, lane);
    }
  float b1c[4];
#pragma unroll
  for (int nt = 0; nt < 4; ++nt) b1c[nt] = b1[nt * 16 + r];

  for (int t = wid; t < NN / 16; t += nw) {
    const int n = t * 16 + r;
    const f4v* xp = (const f4v*)(x + (size_t)n * 64);
    f4v x0 = xp[q * 2],     x1 = xp[q * 2 + 1];
    f4v x2 = xp[8 + q * 2], x3 = xp[8 + q * 2 + 1];
    s8v a0, a1v;
#pragma unroll
    for (int j = 0; j < 4; ++j) {
      a0[j]      = (short)f2bf(x0[j]);
      a0[4 + j]  = (short)f2bf(x1[j]);
      a1v[j]     = (short)f2bf(x2[j]);
      a1v[4 + j] = (short)f2bf(x3[j]);
    }
    *(s8v*)(XB + (size_t)n * 64 + q * 8)      = a0;
    *(s8v*)(XB + (size_t)n * 64 + 32 + q * 8) = a1v;

    f4v aF[4], aG[4];
#pragma unroll
    for (int nt = 0; nt < 4; ++nt) {
      f4v c = {0.f, 0.f, 0.f, 0.f};
      c = MFMA16(a0,  Bt[0][nt], c);
      c = MFMA16(a1v, Bt[1][nt], c);
      aF[nt] = c;
      f4v d = {0.f, 0.f, 0.f, 0.f};
      d = MFMA16(a0,  Bb[0][nt], d);
      d = MFMA16(a1v, Bb[1][nt], d);
      aG[nt] = d;
    }
#pragma unroll
    for (int nt = 0; nt < 4; ++nt)
#pragma unroll
      for (int rg = 0; rg < 4; ++rg) {
        const size_t idx = (size_t)(t * 16 + q * 4 + rg) * 64 + nt * 16 + r;
        F[idx] = f2bf(aF[nt][rg] + b1c[nt]);
        G[idx] = f2bf(aG[nt][rg]);
      }
  }
}

// ---------------------------------------------------------------------------
// Pass B: one block per coarse slab; counting-sort ~4.1K edges into 16 fine
// buckets; emits absolute offsets fofs2[cb][0..16] into slab-addressed ebuf.
// ---------------------------------------------------------------------------
__global__ __launch_bounds__(256) void sort_b_kernel(
    const int* __restrict__ ebufA, const int* __restrict__ cursor,
    int* __restrict__ fofs2, int* __restrict__ ebuf)
{
  __shared__ int lh[4][16];
  __shared__ int cur[16];
  const int cb = blockIdx.x;
  int cnt = cursor[cb * CPAD];
  cnt = cnt < SCAP ? cnt : SCAP;
  const int base = cb * SCAP;
  const int t = threadIdx.x;
  const int wv = t >> 6;
  if (t < 64) lh[t >> 4][t & 15] = 0;
  __syncthreads();
  for (int i = t; i < cnt; i += 256)
    atomicAdd(&lh[wv][(ebufA[base + i] >> 4) & 15], 1);
  __syncthreads();
  if (t == 0) {
    int run = base;
    for (int fb = 0; fb < 16; ++fb) {
      const int v = lh[0][fb] + lh[1][fb] + lh[2][fb] + lh[3][fb];
      cur[fb] = run;
      fofs2[cb * 17 + fb] = run;
      run += v;
    }
    fofs2[cb * 17 + 16] = run;
  }
  __syncthreads();
  for (int i = t; i < cnt; i += 256) {
    const int w = ebufA[base + i];
    const int p = atomicAdd(&cur[(w >> 4) & 15], 1);
    ebuf[p] = w;
  }
}

// ---------------------------------------------------------------------------
// Edge MLP + aggregation: one wave per 16-node fine bucket. RMW-free.
// In-register h2 (swapped MFMA + cvt_pk + permlane32/16), packed sA build,
// packed-f32 prelu, unclamped LOADW (slack masked; src clamped < NN).
// ---------------------------------------------------------------------------
__global__ __launch_bounds__(256) void edge_agg_kernel(
    const unsigned short* __restrict__ F, const unsigned short* __restrict__ G,
    const int* __restrict__ ebuf, const int* __restrict__ fofs2,
    const unsigned short* __restrict__ pack,
    const float* __restrict__ a1p,
    const float* __restrict__ b2, const float* __restrict__ a2p,
    unsigned short* __restrict__ aggb)
{
  const int lane = threadIdx.x & 63;
  const int wv   = threadIdx.x >> 6;
  const int q    = lane >> 4;
  const int r    = lane & 15;

  __shared__ __align__(16) unsigned short ftl[4][16 * FSTR];   // per-wave F tile
  __shared__ __align__(16) unsigned short dbf[4][32];          // per-wave dloc
  unsigned short* ft = ftl[wv];
  unsigned short* db = dbf[wv];

  const int g = blockIdx.x * 4 + wv;
  if (g >= NBKT) return;                      // no block barriers below: safe

  const int cb = g >> 4, fb = g & 15;
  const int start = fofs2[cb * 17 + fb];
  const int end   = fofs2[cb * 17 + fb + 1];
  const int nbase = g * 16;

  s8v W2T[2][4];
#pragma unroll
  for (int kk = 0; kk < 2; ++kk)
#pragma unroll
    for (int ot = 0; ot < 4; ++ot)
      W2T[kk][ot] = ldfrag(pack, 16 + kk * 4 + ot, lane);

  // bias for swapped MFMA: C[row=edge][col=feat] -> per-lane scalar per ot
  float b2c[4];
#pragma unroll
  for (int ot = 0; ot < 4; ++ot) b2c[ot] = b2[ot * 16 + r];

  // uniform scalars -> SGPR
  union { float f; int i; } ua1, ua2;
  ua1.f = a1p[0]; ua1.i = __builtin_amdgcn_readfirstlane(ua1.i);
  ua2.f = a2p[0]; ua2.i = __builtin_amdgcn_readfirstlane(ua2.i);
  const float al1 = ua1.f;
  const float al2 = ua2.f;

  // F tile: 16 rows x 64 -> LDS (coalesced 2KB read), wave-private (DS in-order)
#pragma unroll
  for (int jj = 0; jj < 2; ++jj) {
    const int idx = jj * 64 + lane;
    const int row = idx >> 3, c8 = (idx & 7) * 8;
    s8v v = *(const s8v*)(F + (size_t)(nbase + row) * 64 + c8);
    *(s8v*)(ft + row * FSTR + c8) = v;
  }

  f4v acc[4];
#pragma unroll
  for (int ftx = 0; ftx < 4; ++ftx) acc[ftx] = (f4v){0.f, 0.f, 0.f, 0.f};

#define LOADW(c0, W0, W1)                                            \
  { W0 = ebuf[(c0) + r]; W1 = ebuf[(c0) + 16 + r]; }
#define ISSUEG(W0, W1, GA0, GB0, GA1, GB1)                           \
  { unsigned s0 = ((unsigned)(W0)) >> 9, s1 = ((unsigned)(W1)) >> 9; \
    s0 = s0 < NN ? s0 : 0u; s1 = s1 < NN ? s1 : 0u;                  \
    GA0 = *(const u4v*)(G + (size_t)s0 * 64 + q * 8);                \
    GB0 = *(const u4v*)(G + (size_t)s0 * 64 + 32 + q * 8);           \
    GA1 = *(const u4v*)(G + (size_t)s1 * 64 + q * 8);                \
    GB1 = *(const u4v*)(G + (size_t)s1 * 64 + 32 + q * 8); }

  if (start < end) {
    int w0c, w1c, w0n, w1n;
    u4v ga0c, gb0c, ga1c, gb1c, ga0n, gb0n, ga1n, gb1n;
    LOADW(start, w0c, w1c);
    ISSUEG(w0c, w1c, ga0c, gb0c, ga1c, gb1c);
    LOADW(start + 32, w0n, w1n);

    for (int c0 = start; c0 < end; c0 += 32) {
      const int dl0 = w0c & 15, dl1 = w1c & 15;
      if (q == 0) {
        db[r]      = (unsigned short)((c0 + r < end) ? dl0 : 0xFF);
        db[16 + r] = (unsigned short)((c0 + 16 + r < end) ? dl1 : 0xFF);
      }
      // F rows from LDS tile
      u4v fa0 = *(const u4v*)(ft + dl0 * FSTR + q * 8);
      u4v fb0 = *(const u4v*)(ft + dl0 * FSTR + 32 + q * 8);
      u4v fa1 = *(const u4v*)(ft + dl1 * FSTR + q * 8);
      u4v fb1 = *(const u4v*)(ft + dl1 * FSTR + 32 + q * 8);

      union { u4v u; s8v s; } P00, P01, P10, P11;
#pragma unroll
      for (int j = 0; j < 4; ++j) {
        P00.u[j] = h1pair(fa0[j], ga0c[j], al1);
        P01.u[j] = h1pair(fb0[j], gb0c[j], al1);
        P10.u[j] = h1pair(fa1[j], ga1c[j], al1);
        P11.u[j] = h1pair(fb1[j], gb1c[j], al1);
      }

      // G registers consumed -> launch next chunk's gathers + future words
      ISSUEG(w0n, w1n, ga0n, gb0n, ga1n, gb1n);
      int w0f, w1f;
      LOADW(c0 + 64, w0f, w1f);

      // S^T indicator A-frag: A[m=node=r][k=edge=q*8+j], packed build.
      u4v dvw = *(const u4v*)(db + q * 8);
      const unsigned rr = (unsigned)r * 0x00010001u;
      union { unsigned w[4]; s8v s; } sAu;
#pragma unroll
      for (int k = 0; k < 4; ++k) {
        unsigned x = dvw[k] ^ rr;
        unsigned m, t;
        asm("v_pk_min_u16 %0, %1, %2" : "=v"(m) : "v"(x), "s"(0x00010001u));
        asm("v_pk_sub_i16 %0, %1, %2" : "=v"(t) : "v"(m), "s"(0x00010001u));
        sAu.w[k] = t & 0x3F803F80u;
      }
      const s8v sA = sAu.s;

      // Swapped h2-MFMA + cvt_pk + permlane quarters -> agg B-frag dwords.
#pragma unroll
      for (int ot = 0; ot < 4; ++ot) {
        const float bb = b2c[ot];
        const f4v binit = {bb, bb, bb, bb};
        f4v c = binit;
        c = MFMA16(P00.s, W2T[0][ot], c);
        c = MFMA16(P01.s, W2T[1][ot], c);
        f4v d = binit;
        d = MFMA16(P10.s, W2T[0][ot], d);
        d = MFMA16(P11.s, W2T[1][ot], d);
        f4v cm = __builtin_elementwise_max(c, c * al2);
        f4v dm = __builtin_elementwise_max(d, d * al2);
        unsigned pc0, pc1, pd0, pd1;
        asm("v_cvt_pk_bf16_f32 %0, %1, %2" : "=v"(pc0) : "v"(cm.x), "v"(cm.y));
        asm("v_cvt_pk_bf16_f32 %0, %1, %2" : "=v"(pc1) : "v"(cm.z), "v"(cm.w));
        asm("v_cvt_pk_bf16_f32 %0, %1, %2" : "=v"(pd0) : "v"(dm.x), "v"(dm.y));
        asm("v_cvt_pk_bf16_f32 %0, %1, %2" : "=v"(pd1) : "v"(dm.z), "v"(dm.w));
        asm("v_permlane32_swap_b32 %0, %1" : "+v"(pc0), "+v"(pd0));
        asm("v_permlane16_swap_b32 %0, %1" : "+v"(pc0), "+v"(pd0));
        asm("v_permlane32_swap_b32 %0, %1" : "+v"(pc1), "+v"(pd1));
        asm("v_permlane16_swap_b32 %0, %1" : "+v"(pc1), "+v"(pd1));
        union { unsigned w[4]; s8v s; } Bf;
        Bf.w[0] = pc0;  // edges q*8+0,1
        Bf.w[1] = pc1;  // edges q*8+2,3
        Bf.w[2] = pd0;  // edges q*8+4,5
        Bf.w[3] = pd1;  // edges q*8+6,7
        acc[ot] = MFMA16(sA, Bf.s, acc[ot]);
      }

      // rotate pipeline
      w0c = w0n; w1c = w1n; w0n = w0f; w1n = w1f;
      ga0c = ga0n; gb0c = gb0n; ga1c = ga1n; gb1c = gb1n;
    }
  }
#undef LOADW
#undef ISSUEG

  // flush: one bf16 store per (node, feature)
#pragma unroll
  for (int ftx = 0; ftx < 4; ++ftx)
#pragma unroll
    for (int rg = 0; rg < 4; ++rg) {
      const int node = nbase + q * 4 + rg;
      aggb[(size_t)node * 64 + ftx * 16 + r] = f2bf(acc[ftx][rg]);
    }
}

// ---------------------------------------------------------------------------
// Node MLP: z = prelu(prelu(cat(x,agg) @ W3 + b3) @ W4 + b4, a_blk)
// BN partials: per-wave shfl reduce -> red[4][128] LDS (plain stores) ->
// __syncthreads -> threads 0..127 do ONE global atomicAdd each (G12:
// block-level reduction first; 391 line-transactions per address total,
// and consecutive-lane addresses merge within one instruction).
// ---------------------------------------------------------------------------
__global__ __launch_bounds__(256) void node_mlp_kernel(
    const unsigned short* __restrict__ XB,
    const unsigned short* __restrict__ aggb,
    const unsigned short* __restrict__ pack,
    const float* __restrict__ b3, const float* __restrict__ a3p,
    const float* __restrict__ b4, const float* __restrict__ ablkp,
    unsigned short* __restrict__ zb,
    float* __restrict__ part)
{
  const int lane = threadIdx.x & 63;
  const int wv   = threadIdx.x >> 6;
  const int q    = lane >> 4;
  const int r    = lane & 15;
  const int nw   = gridDim.x * 4;
  const int wid  = blockIdx.x * 4 + wv;

  s8v B3f[4][4];
  s8v B4f[2][4];
#pragma unroll
  for (int kk = 0; kk < 4; ++kk)
#pragma unroll
    for (int nt = 0; nt < 4; ++nt)
      B3f[kk][nt] = ldfrag(pack, 24 + kk * 4 + nt, lane);
#pragma unroll
  for (int kk = 0; kk < 2; ++kk)
#pragma unroll
    for (int nt = 0; nt < 4; ++nt)
      B4f[kk][nt] = ldfrag(pack, 40 + kk * 4 + nt, lane);

  float bias3[4], bias4[4];
#pragma unroll
  for (int nt = 0; nt < 4; ++nt) { bias3[nt] = b3[nt * 16 + r]; bias4[nt] = b4[nt * 16 + r]; }
  const float al3 = a3p[0];
  const float alb = ablkp[0];

  __shared__ __align__(16) unsigned short hbuf[4][16 * 72];
  __shared__ float red[4][128];
  unsigned short* hb = hbuf[wv];

  float bs[4] = {0.f, 0.f, 0.f, 0.f};
  float bq[4] = {0.f, 0.f, 0.f, 0.f};

  for (int t = wid; t < NN / 16; t += nw) {
    const int n = t * 16 + r;
    const s8v* xn = (const s8v*)(XB + (size_t)n * 64);
    const s8v* an = (const s8v*)(aggb + (size_t)n * 64);
    s8v a0  = xn[q];
    s8v a1v = xn[q + 4];
    s8v a2v = an[q];
    s8v a3v = an[q + 4];

    f4v acc[4];
#pragma unroll
    for (int nt = 0; nt < 4; ++nt) {
      f4v c = {0.f, 0.f, 0.f, 0.f};
      c = MFMA16(a0,  B3f[0][nt], c);
      c = MFMA16(a1v, B3f[1][nt], c);
      c = MFMA16(a2v, B3f[2][nt], c);
      c = MFMA16(a3v, B3f[3][nt], c);
      acc[nt] = c;
    }

#pragma unroll
    for (int nt = 0; nt < 4; ++nt)
#pragma unroll
      for (int rg = 0; rg < 4; ++rg) {
        float v = prelu_m(acc[nt][rg] + bias3[nt], al3);
        hb[(q * 4 + rg) * 72 + nt * 16 + r] = f2bf(v);
      }
    s8v p0 = *(const s8v*)(hb + r * 72 + q * 8);
    s8v p1 = *(const s8v*)(hb + r * 72 + 32 + q * 8);

    f4v acc2[4];
#pragma unroll
    for (int nt = 0; nt < 4; ++nt) {
      f4v c = {0.f, 0.f, 0.f, 0.f};
      c = MFMA16(p0, B4f[0][nt], c);
      c = MFMA16(p1, B4f[1][nt], c);
      acc2[nt] = c;
    }

#pragma unroll
    for (int nt = 0; nt < 4; ++nt)
#pragma unroll
      for (int rg = 0; rg < 4; ++rg) {
        float v = prelu_m(acc2[nt][rg] + bias4[nt], alb);
        const int row = t * 16 + q * 4 + rg;
        zb[(size_t)row * 64 + nt * 16 + r] = f2bf(v);
        bs[nt] += v;
        bq[nt] += v * v;
      }
  }

  // per-wave shfl reduce -> lanes q==0 hold per-(nt,r) partials -> LDS
#pragma unroll
  for (int nt = 0; nt < 4; ++nt) {
    float s = bs[nt];
    s += __shfl_xor(s, 16, 64);
    s += __shfl_xor(s, 32, 64);
    float ss = bq[nt];
    ss += __shfl_xor(ss, 16, 64);
    ss += __shfl_xor(ss, 32, 64);
    if (q == 0) {
      red[wv][nt * 16 + r]      = s;
      red[wv][64 + nt * 16 + r] = ss;
    }
  }
  __syncthreads();
  if (threadIdx.x < 128) {
    const int t = threadIdx.x;
    atomicAdd(&part[t], red[0][t] + red[1][t] + red[2][t] + red[3][t]);
  }
}

// ---------------------------------------------------------------------------
// BatchNorm finalize: grid-stride stream; reads z (bf16) + partials
// ---------------------------------------------------------------------------
__global__ __launch_bounds__(256) void bn_kernel(
    const unsigned short* __restrict__ zb,
    float* __restrict__ out,
    const float* __restrict__ part,
    const float* __restrict__ gamma,
    const float* __restrict__ beta)
{
  const size_t total = (size_t)NN * 16;   // quads of 4 elems
  const float inv_n = 1.0f / (float)NN;
  for (size_t i = (size_t)blockIdx.x * 256 + threadIdx.x; i < total;
       i += (size_t)gridDim.x * 256) {
    ushort4 v = ((const ushort4*)zb)[i];
    unsigned short e[4] = {v.x, v.y, v.z, v.w};
    float o[4];
    const int f0 = (int)((i * 4) & 63);
#pragma unroll
    for (int j = 0; j < 4; ++j) {
      const int f = f0 + j;
      const float mean = part[f] * inv_n;
      const float var  = part[64 + f] * inv_n - mean * mean;
      const float sc = rsqrtf(var + BN_EPS) * gamma[f];
      const float sh = beta[f] - mean * sc;
      o[j] = bf2f(e[j]) * sc + sh;
    }
    ((float4*)out)[i] = make_float4(o[0], o[1], o[2], o[3]);
  }
}

extern "C" void kernel_launch(void* const* d_in, const int* in_sizes, int n_in,
                              void* d_out, int out_size, void* d_ws, size_t ws_size,
                              hipStream_t stream) {
  const float* x  = (const float*)d_in[0];
  const int* ei   = (const int*)d_in[1];
  const float* W1 = (const float*)d_in[2];
  const float* b1 = (const float*)d_in[3];
  const float* a1 = (const float*)d_in[4];
  const float* W2 = (const float*)d_in[5];
  const float* b2 = (const float*)d_in[6];
  const float* a2 = (const float*)d_in[7];
  const float* W3 = (const float*)d_in[8];
  const float* b3 = (const float*)d_in[9];
  const float* a3 = (const float*)d_in[10];
  const float* W4 = (const float*)d_in[11];
  const float* b4 = (const float*)d_in[12];
  const float* ab = (const float*)d_in[13];
  const float* gm = (const float*)d_in[14];
  const float* bt = (const float*)d_in[15];

  float* part          = (float*)d_ws;                    // [128] f32 (+pad)
  unsigned short* aggb = (unsigned short*)(part + 2048);  // [NN*64] bf16
  unsigned short* F    = aggb + (size_t)NN * 64;          // [NN*64] bf16 (+b1)
  unsigned short* G    = F + (size_t)NN * 64;             // [NN*64] bf16
  unsigned short* XB   = G + (size_t)NN * 64;             // [NN*64] bf16
  unsigned short* zb   = XB + (size_t)NN * 64;            // [NN*64] bf16
  int* cursor          = (int*)(zb + (size_t)NN * 64);    // [CB*CPAD] padded
  int* fofs2           = cursor + (size_t)CB * CPAD;      // [CB*17] (+pad)
  int* ebufA           = fofs2 + CB * 17 + 8;             // [CB*SCAP]
  int* ebuf            = ebufA + (size_t)CB * SCAP;       // [CB*SCAP + 128]
  unsigned short* pack = (unsigned short*)(ebuf + (size_t)CB * SCAP + 128);
  float* out           = (float*)d_out;

  const int* srcp = ei;        // edge_index[0] = src (x_j)
  const int* dstp = ei + NE;   // edge_index[1] = dst (x_i)

  pack_kernel<<<dim3(1), dim3(256), 0, stream>>>(W1, W2, W3, W4, pack, part, cursor);
  pre_scatter_kernel<<<dim3(NBLKA + NPREB), dim3(256), 0, stream>>>(
      x, pack, b1, F, G, XB, srcp, dstp, cursor, ebufA);
  sort_b_kernel<<<dim3(CB), dim3(256), 0, stream>>>(ebufA, cursor, fofs2, ebuf);
  edge_agg_kernel<<<dim3((NBKT + 3) / 4), dim3(256), 0, stream>>>(
      F, G, ebuf, fofs2, pack, a1, b2, a2, aggb);
  node_mlp_kernel<<<dim3(391), dim3(256), 0, stream>>>(
      XB, aggb, pack, b3, a3, b4, ab, zb, part);
  bn_kernel<<<dim3(2048), dim3(256), 0, stream>>>(zb, out, part, gm, bt);
}

// Round 10
// 226.917 us; speedup vs baseline: 1.4488x; 1.0318x over previous
//
#include <hip/hip_runtime.h>

#define NN 100000
#define NE 1600000
#define BN_EPS 1e-5f
#define NBKT 6250         // fine buckets of 16 nodes (g = dst>>4)
#define CB 392            // coarse buckets of 256 nodes (cb = dst>>8; 391 used)
#define SCAP 4864         // slab capacity per coarse bucket (mean 4096, +12 sigma)
#define CPAD 16           // cursor stride in ints (64B)
#define NBLKA 400         // scatter blocks (fused kernel, blockIdx < NBLKA)
#define NPREB 391         // pre_gemm blocks (fused kernel, blockIdx >= NBLKA)
#define EPA 4000          // edges per scatter block (400*4000 = NE)
#define FSTR 72           // LDS F-tile row stride in shorts (144B rows, 16B-aligned)
#define NFRAG 48          // packed weight fragments

typedef short s8v __attribute__((ext_vector_type(8)));
typedef float f4v __attribute__((ext_vector_type(4)));
typedef float f2v __attribute__((ext_vector_type(2)));
typedef unsigned u4v __attribute__((ext_vector_type(4)));

__device__ __forceinline__ float bf2f(unsigned short u) {
  union { unsigned u; float f; } v; v.u = ((unsigned)u) << 16; return v.f;
}
__device__ __forceinline__ unsigned fbits(float f) {
  union { float f; unsigned u; } v; v.f = f; return v.u;
}
__device__ __forceinline__ float bcast(unsigned u) {
  union { unsigned u; float f; } v; v.u = u; return v.f;
}
// round-half-up bf16 (ties differ from RNE with prob 2^-16 — negligible)
__device__ __forceinline__ unsigned short f2bf(float f) {
  return (unsigned short)((fbits(f) + 0x8000u) >> 16);
}
__device__ __forceinline__ s8v ldfrag(const unsigned short* __restrict__ pack,
                                      int f, int lane) {
  return *(const s8v*)(pack + ((size_t)f * 64 + lane) * 8);
}
// prelu(x) = max(x, a*x) — exact for 0 <= a <= 1 (a == 0.25 here)
__device__ __forceinline__ float prelu_m(float x, float a) { return fmaxf(x, a * x); }

// h1 on one dword pair (2 bf16 elems of F and G); packed-f32 add/mul/max
// + RNE pack via v_cvt_pk_bf16_f32
__device__ __forceinline__ unsigned h1pair(unsigned fd, unsigned gd, float al) {
  f2v fv = { bcast(fd << 16), bcast(fd & 0xFFFF0000u) };
  f2v gv = { bcast(gd << 16), bcast(gd & 0xFFFF0000u) };
  f2v s = fv + gv;
  f2v m = __builtin_elementwise_max(s, s * al);
  unsigned rr;
  asm("v_cvt_pk_bf16_f32 %0, %1, %2" : "=v"(rr) : "v"(m.x), "v"(m.y));
  return rr;
}

#define MFMA16(a, b, c) __builtin_amdgcn_mfma_f32_16x16x32_bf16((a), (b), (c), 0, 0, 0)

// perfect shuffle of lane quarters: (X,Y) -> X=(X.q0,X.q2,Y.q0,Y.q2),
// Y=(X.q1,X.q3,Y.q1,Y.q3). Verified primitive (rounds 3-9 h2 path + round 6
// epilogue, all refcheck-passing).
#define QSHUF(xx, yy)                                                \
  { asm("v_permlane32_swap_b32 %0, %1" : "+v"(xx), "+v"(yy));        \
    asm("v_permlane16_swap_b32 %0, %1" : "+v"(xx), "+v"(yy)); }

// ---------------------------------------------------------------------------
// Weight pack (one-shot) + BN-partial zeroing + cursor zeroing.
// frag map: 0..7 W1 top | 8..15 W1 bot | 16..23 W2 | 24..39 W3 | 40..47 W4
// ---------------------------------------------------------------------------
__global__ __launch_bounds__(256) void pack_kernel(
    const float* __restrict__ W1, const float* __restrict__ W2,
    const float* __restrict__ W3, const float* __restrict__ W4,
    unsigned short* __restrict__ pack, float* __restrict__ part,
    int* __restrict__ cursor)
{
  if (threadIdx.x < 128) part[threadIdx.x] = 0.f;
  for (int i = threadIdx.x; i < CB * CPAD; i += 256) cursor[i] = 0;
  for (int it = threadIdx.x; it < NFRAG * 64; it += 256) {
    const int f = it >> 6;
    const int lane = it & 63;
    const int q = lane >> 4, r = lane & 15;
    const float* src; int rowoff, fi;
    if (f < 8)       { src = W1; rowoff = 0;  fi = f; }
    else if (f < 16) { src = W1; rowoff = 64; fi = f - 8; }
    else if (f < 24) { src = W2; rowoff = 0;  fi = f - 16; }
    else if (f < 40) { src = W3; rowoff = 0;  fi = f - 24; }
    else             { src = W4; rowoff = 0;  fi = f - 40; }
    const int kk = fi >> 2, nt = fi & 3;
    unsigned short tmp[8];
#pragma unroll
    for (int j = 0; j < 8; ++j)
      tmp[j] = f2bf(src[(size_t)(rowoff + kk * 32 + q * 8 + j) * 64 + nt * 16 + r]);
    *(s8v*)(pack + ((size_t)f * 64 + lane) * 8) = *(const s8v*)tmp;
  }
}

// ---------------------------------------------------------------------------
// FUSED: edge scatter (blocks 0..NBLKA-1) || pre-GEMM (blocks NBLKA..).
// ---------------------------------------------------------------------------
__global__ __launch_bounds__(256) void pre_scatter_kernel(
    const float* __restrict__ x, const unsigned short* __restrict__ pack,
    const float* __restrict__ b1,
    unsigned short* __restrict__ F, unsigned short* __restrict__ G,
    unsigned short* __restrict__ XB,
    const int* __restrict__ srcp, const int* __restrict__ dstp,
    int* __restrict__ cursor, int* __restrict__ ebufA)
{
  __shared__ int lh[CB];
  __shared__ int lbase[CB];

  if (blockIdx.x < NBLKA) {
    // ---- scatter phase ----
    const int t = threadIdx.x;
    for (int i = t; i < CB; i += 256) lh[i] = 0;
    __syncthreads();
    const int base = blockIdx.x * EPA;
    for (int o = t; o < EPA; o += 256)
      atomicAdd(&lh[dstp[base + o] >> 8], 1);
    __syncthreads();
    for (int i = t; i < CB; i += 256) {
      const int c = lh[i];
      lbase[i] = c ? atomicAdd(&cursor[i * CPAD], c) : 0;
      lh[i] = 0;
    }
    __syncthreads();
    for (int o = t; o < EPA; o += 256) {
      const int d = dstp[base + o];
      const int s = srcp[base + o];
      const int cb = d >> 8;
      const int p = atomicAdd(&lh[cb], 1);
      ebufA[(size_t)cb * SCAP + lbase[cb] + p] = (s << 9) | (d & 511);
    }
    return;
  }

  // ---- pre_gemm phase ----
  const int lane = threadIdx.x & 63;
  const int wv   = threadIdx.x >> 6;
  const int q    = lane >> 4;
  const int r    = lane & 15;
  const int nw   = NPREB * 4;
  const int wid  = (blockIdx.x - NBLKA) * 4 + wv;

  s8v Bt[2][4], Bb[2][4];
#pragma unroll
  for (int kk = 0; kk < 2; ++kk)
#pragma unroll
    for (int nt = 0; nt < 4; ++nt) {
      Bt[kk][nt] = ldfrag(pack, kk * 4 + nt, lane);
      Bb[kk][nt] = ldfrag(pack, 8 + kk * 4 + nt, lane);
    }
  float b1c[4];
#pragma unroll
  for (int nt = 0; nt < 4; ++nt) b1c[nt] = b1[nt * 16 + r];

  for (int t = wid; t < NN / 16; t += nw) {
    const int n = t * 16 + r;
    const f4v* xp = (const f4v*)(x + (size_t)n * 64);
    f4v x0 = xp[q * 2],     x1 = xp[q * 2 + 1];
    f4v x2 = xp[8 + q * 2], x3 = xp[8 + q * 2 + 1];
    s8v a0, a1v;
#pragma unroll
    for (int j = 0; j < 4; ++j) {
      a0[j]      = (short)f2bf(x0[j]);
      a0[4 + j]  = (short)f2bf(x1[j]);
      a1v[j]     = (short)f2bf(x2[j]);
      a1v[4 + j] = (short)f2bf(x3[j]);
    }
    *(s8v*)(XB + (size_t)n * 64 + q * 8)      = a0;
    *(s8v*)(XB + (size_t)n * 64 + 32 + q * 8) = a1v;

    f4v aF[4], aG[4];
#pragma unroll
    for (int nt = 0; nt < 4; ++nt) {
      f4v c = {0.f, 0.f, 0.f, 0.f};
      c = MFMA16(a0,  Bt[0][nt], c);
      c = MFMA16(a1v, Bt[1][nt], c);
      aF[nt] = c;
      f4v d = {0.f, 0.f, 0.f, 0.f};
      d = MFMA16(a0,  Bb[0][nt], d);
      d = MFMA16(a1v, Bb[1][nt], d);
      aG[nt] = d;
    }
#pragma unroll
    for (int nt = 0; nt < 4; ++nt)
#pragma unroll
      for (int rg = 0; rg < 4; ++rg) {
        const size_t idx = (size_t)(t * 16 + q * 4 + rg) * 64 + nt * 16 + r;
        F[idx] = f2bf(aF[nt][rg] + b1c[nt]);
        G[idx] = f2bf(aG[nt][rg]);
      }
  }
}

// ---------------------------------------------------------------------------
// Pass B: one block per coarse slab; counting-sort ~4.1K edges into 16 fine
// buckets; emits absolute offsets fofs2[cb][0..16] into slab-addressed ebuf.
// ---------------------------------------------------------------------------
__global__ __launch_bounds__(256) void sort_b_kernel(
    const int* __restrict__ ebufA, const int* __restrict__ cursor,
    int* __restrict__ fofs2, int* __restrict__ ebuf)
{
  __shared__ int lh[4][16];
  __shared__ int cur[16];
  const int cb = blockIdx.x;
  int cnt = cursor[cb * CPAD];
  cnt = cnt < SCAP ? cnt : SCAP;
  const int base = cb * SCAP;
  const int t = threadIdx.x;
  const int wv = t >> 6;
  if (t < 64) lh[t >> 4][t & 15] = 0;
  __syncthreads();
  for (int i = t; i < cnt; i += 256)
    atomicAdd(&lh[wv][(ebufA[base + i] >> 4) & 15], 1);
  __syncthreads();
  if (t == 0) {
    int run = base;
    for (int fb = 0; fb < 16; ++fb) {
      const int v = lh[0][fb] + lh[1][fb] + lh[2][fb] + lh[3][fb];
      cur[fb] = run;
      fofs2[cb * 17 + fb] = run;
      run += v;
    }
    fofs2[cb * 17 + 16] = run;
  }
  __syncthreads();
  for (int i = t; i < cnt; i += 256) {
    const int w = ebufA[base + i];
    const int p = atomicAdd(&cur[(w >> 4) & 15], 1);
    ebuf[p] = w;
  }
}

// ---------------------------------------------------------------------------
// FUSED edge MLP + aggregation + node MLP (round-6 verified structure with
// round-9's block-reduced BN atomics). One wave per 16-node fine bucket.
// Agg MFMA operand-SWAPPED (A=H2^T frag, B=S indicator) -> acc = agg^T:
// lane(q,r) holds agg[node=r][feat=ot*16+q*4+rg]. cvt_pk + QSHUF build the
// node-MLP agg A-frags in-register; node MLP + BN partials run in-wave.
// No aggb round-trip (25.6MB saved), one fewer dispatch.
// NOTE: no early return — all waves reach the block-reduction barrier.
// ---------------------------------------------------------------------------
__global__ __launch_bounds__(256) void edge_agg_kernel(
    const unsigned short* __restrict__ F, const unsigned short* __restrict__ G,
    const int* __restrict__ ebuf, const int* __restrict__ fofs2,
    const unsigned short* __restrict__ pack,
    const float* __restrict__ a1p,
    const float* __restrict__ b2, const float* __restrict__ a2p,
    const unsigned short* __restrict__ XB,
    const float* __restrict__ b3, const float* __restrict__ a3p,
    const float* __restrict__ b4, const float* __restrict__ ablkp,
    unsigned short* __restrict__ zb, float* __restrict__ part)
{
  const int lane = threadIdx.x & 63;
  const int wv   = threadIdx.x >> 6;
  const int q    = lane >> 4;
  const int r    = lane & 15;

  __shared__ __align__(16) unsigned short ftl[4][16 * FSTR];   // F tile / h3 buf
  __shared__ __align__(16) unsigned short dbf[4][32];          // per-wave dloc
  __shared__ float red[4][128];                                // BN block-reduce
  unsigned short* ft = ftl[wv];
  unsigned short* db = dbf[wv];

  const int g = blockIdx.x * 4 + wv;
  const bool active = g < NBKT;

  float bs[4] = {0.f, 0.f, 0.f, 0.f};
  float bq[4] = {0.f, 0.f, 0.f, 0.f};

  if (active) {
    const int cb = g >> 4, fb = g & 15;
    const int start = fofs2[cb * 17 + fb];
    const int end   = fofs2[cb * 17 + fb + 1];
    const int nbase = g * 16;

    s8v W2T[2][4];
#pragma unroll
    for (int kk = 0; kk < 2; ++kk)
#pragma unroll
      for (int ot = 0; ot < 4; ++ot)
        W2T[kk][ot] = ldfrag(pack, 16 + kk * 4 + ot, lane);

    // bias for swapped h2-MFMA: C[row=edge][col=feat] -> per-lane per ot
    float b2c[4];
#pragma unroll
    for (int ot = 0; ot < 4; ++ot) b2c[ot] = b2[ot * 16 + r];

    union { float f; int i; } ua1, ua2;
    ua1.f = a1p[0]; ua1.i = __builtin_amdgcn_readfirstlane(ua1.i);
    ua2.f = a2p[0]; ua2.i = __builtin_amdgcn_readfirstlane(ua2.i);
    const float al1 = ua1.f;
    const float al2 = ua2.f;

    // F tile: 16 rows x 64 -> LDS (wave-private, DS in-order)
#pragma unroll
    for (int jj = 0; jj < 2; ++jj) {
      const int idx = jj * 64 + lane;
      const int row = idx >> 3, c8 = (idx & 7) * 8;
      s8v v = *(const s8v*)(F + (size_t)(nbase + row) * 64 + c8);
      *(s8v*)(ft + row * FSTR + c8) = v;
    }

    f4v acc[4];
#pragma unroll
    for (int ftx = 0; ftx < 4; ++ftx) acc[ftx] = (f4v){0.f, 0.f, 0.f, 0.f};

#define LOADW(c0, W0, W1)                                            \
  { W0 = ebuf[(c0) + r]; W1 = ebuf[(c0) + 16 + r]; }
#define ISSUEG(W0, W1, GA0, GB0, GA1, GB1)                           \
  { unsigned s0 = ((unsigned)(W0)) >> 9, s1 = ((unsigned)(W1)) >> 9; \
    s0 = s0 < NN ? s0 : 0u; s1 = s1 < NN ? s1 : 0u;                  \
    GA0 = *(const u4v*)(G + (size_t)s0 * 64 + q * 8);                \
    GB0 = *(const u4v*)(G + (size_t)s0 * 64 + 32 + q * 8);           \
    GA1 = *(const u4v*)(G + (size_t)s1 * 64 + q * 8);                \
    GB1 = *(const u4v*)(G + (size_t)s1 * 64 + 32 + q * 8); }

    if (start < end) {
      int w0c, w1c, w0n, w1n;
      u4v ga0c, gb0c, ga1c, gb1c, ga0n, gb0n, ga1n, gb1n;
      LOADW(start, w0c, w1c);
      ISSUEG(w0c, w1c, ga0c, gb0c, ga1c, gb1c);
      LOADW(start + 32, w0n, w1n);

      for (int c0 = start; c0 < end; c0 += 32) {
        const int dl0 = w0c & 15, dl1 = w1c & 15;
        if (q == 0) {
          db[r]      = (unsigned short)((c0 + r < end) ? dl0 : 0xFF);
          db[16 + r] = (unsigned short)((c0 + 16 + r < end) ? dl1 : 0xFF);
        }
        // F rows from LDS tile
        u4v fa0 = *(const u4v*)(ft + dl0 * FSTR + q * 8);
        u4v fb0 = *(const u4v*)(ft + dl0 * FSTR + 32 + q * 8);
        u4v fa1 = *(const u4v*)(ft + dl1 * FSTR + q * 8);
        u4v fb1 = *(const u4v*)(ft + dl1 * FSTR + 32 + q * 8);

        union { u4v u; s8v s; } P00, P01, P10, P11;
#pragma unroll
        for (int j = 0; j < 4; ++j) {
          P00.u[j] = h1pair(fa0[j], ga0c[j], al1);
          P01.u[j] = h1pair(fb0[j], gb0c[j], al1);
          P10.u[j] = h1pair(fa1[j], ga1c[j], al1);
          P11.u[j] = h1pair(fb1[j], gb1c[j], al1);
        }

        // G registers consumed -> launch next chunk's gathers + future words
        ISSUEG(w0n, w1n, ga0n, gb0n, ga1n, gb1n);
        int w0f, w1f;
        LOADW(c0 + 64, w0f, w1f);

        // S indicator: lane(q,r) dword k: 0x3F80 halves iff dloc==r
        u4v dvw = *(const u4v*)(db + q * 8);
        const unsigned rr = (unsigned)r * 0x00010001u;
        union { unsigned w[4]; s8v s; } sAu;
#pragma unroll
        for (int k = 0; k < 4; ++k) {
          unsigned x = dvw[k] ^ rr;
          unsigned m, t;
          asm("v_pk_min_u16 %0, %1, %2" : "=v"(m) : "v"(x), "s"(0x00010001u));
          asm("v_pk_sub_i16 %0, %1, %2" : "=v"(t) : "v"(m), "s"(0x00010001u));
          sAu.w[k] = t & 0x3F803F80u;
        }
        const s8v sA = sAu.s;

        // Swapped h2-MFMA: D[m=edge][n=feat]; cvt_pk + QSHUF -> H2^T frag.
#pragma unroll
        for (int ot = 0; ot < 4; ++ot) {
          const float bb = b2c[ot];
          const f4v binit = {bb, bb, bb, bb};
          f4v c = binit;
          c = MFMA16(P00.s, W2T[0][ot], c);
          c = MFMA16(P01.s, W2T[1][ot], c);
          f4v d = binit;
          d = MFMA16(P10.s, W2T[0][ot], d);
          d = MFMA16(P11.s, W2T[1][ot], d);
          f4v cm = __builtin_elementwise_max(c, c * al2);
          f4v dm = __builtin_elementwise_max(d, d * al2);
          unsigned pc0, pc1, pd0, pd1;
          asm("v_cvt_pk_bf16_f32 %0, %1, %2" : "=v"(pc0) : "v"(cm.x), "v"(cm.y));
          asm("v_cvt_pk_bf16_f32 %0, %1, %2" : "=v"(pc1) : "v"(cm.z), "v"(cm.w));
          asm("v_cvt_pk_bf16_f32 %0, %1, %2" : "=v"(pd0) : "v"(dm.x), "v"(dm.y));
          asm("v_cvt_pk_bf16_f32 %0, %1, %2" : "=v"(pd1) : "v"(dm.z), "v"(dm.w));
          QSHUF(pc0, pd0);
          QSHUF(pc1, pd1);
          union { unsigned w[4]; s8v s; } Bf;
          Bf.w[0] = pc0;  // edges q*8+0,1
          Bf.w[1] = pc1;  // edges q*8+2,3
          Bf.w[2] = pd0;  // edges q*8+4,5
          Bf.w[3] = pd1;  // edges q*8+6,7
          // SWAPPED agg MFMA: acc = H2^T @ S = agg^T
          acc[ot] = MFMA16(Bf.s, sA, acc[ot]);
        }

        // rotate pipeline
        w0c = w0n; w1c = w1n; w0n = w0f; w1n = w1f;
        ga0c = ga0n; gb0c = gb0n; ga1c = ga1n; gb1c = gb1n;
      }
    }
#undef LOADW
#undef ISSUEG

    // ---- fused node MLP epilogue (round-6 verified layout) ----------------
    // acc = agg^T: lane(q,r) holds agg[node=nbase+r][feat=ot*16+q*4+rg].
    unsigned Xp00, Xp01, Xp10, Xp11, Xp20, Xp21, Xp30, Xp31;
    asm("v_cvt_pk_bf16_f32 %0, %1, %2" : "=v"(Xp00) : "v"(acc[0][0]), "v"(acc[0][1]));
    asm("v_cvt_pk_bf16_f32 %0, %1, %2" : "=v"(Xp01) : "v"(acc[0][2]), "v"(acc[0][3]));
    asm("v_cvt_pk_bf16_f32 %0, %1, %2" : "=v"(Xp10) : "v"(acc[1][0]), "v"(acc[1][1]));
    asm("v_cvt_pk_bf16_f32 %0, %1, %2" : "=v"(Xp11) : "v"(acc[1][2]), "v"(acc[1][3]));
    asm("v_cvt_pk_bf16_f32 %0, %1, %2" : "=v"(Xp20) : "v"(acc[2][0]), "v"(acc[2][1]));
    asm("v_cvt_pk_bf16_f32 %0, %1, %2" : "=v"(Xp21) : "v"(acc[2][2]), "v"(acc[2][3]));
    asm("v_cvt_pk_bf16_f32 %0, %1, %2" : "=v"(Xp30) : "v"(acc[3][0]), "v"(acc[3][1]));
    asm("v_cvt_pk_bf16_f32 %0, %1, %2" : "=v"(Xp31) : "v"(acc[3][2]), "v"(acc[3][3]));
    QSHUF(Xp00, Xp10);   // Xp00 = agg feats q*8+0,1 | Xp10 = q*8+4,5
    QSHUF(Xp01, Xp11);   // Xp01 = q*8+2,3 | Xp11 = q*8+6,7
    QSHUF(Xp20, Xp30);   // feats 32+: same pattern
    QSHUF(Xp21, Xp31);
    union { unsigned w[4]; s8v s; } A2f, A3f;
    A2f.w[0] = Xp00; A2f.w[1] = Xp01; A2f.w[2] = Xp10; A2f.w[3] = Xp11;
    A3f.w[0] = Xp20; A3f.w[1] = Xp21; A3f.w[2] = Xp30; A3f.w[3] = Xp31;

    const s8v* xn = (const s8v*)(XB + (size_t)(nbase + r) * 64);
    const s8v a0  = xn[q];
    const s8v a1v = xn[q + 4];

    f4v acc3[4];
#pragma unroll
    for (int nt = 0; nt < 4; ++nt) {
      f4v c = {0.f, 0.f, 0.f, 0.f};
      c = MFMA16(a0,    ldfrag(pack, 24 + 0 + nt, lane), c);
      c = MFMA16(a1v,   ldfrag(pack, 24 + 4 + nt, lane), c);
      c = MFMA16(A2f.s, ldfrag(pack, 24 + 8 + nt, lane), c);
      c = MFMA16(A3f.s, ldfrag(pack, 24 + 12 + nt, lane), c);
      acc3[nt] = c;
    }

    union { float f; int i; } ua3, uab;
    ua3.f = a3p[0]; ua3.i = __builtin_amdgcn_readfirstlane(ua3.i);
    uab.f = ablkp[0]; uab.i = __builtin_amdgcn_readfirstlane(uab.i);
    const float al3 = ua3.f;
    const float alb = uab.f;

    float bias3[4], bias4[4];
#pragma unroll
    for (int nt = 0; nt < 4; ++nt) { bias3[nt] = b3[nt * 16 + r]; bias4[nt] = b4[nt * 16 + r]; }

    // h3 -> LDS (reuse ft; wave-private, DS in-order) -> A-frags for W4
#pragma unroll
    for (int nt = 0; nt < 4; ++nt)
#pragma unroll
      for (int rg = 0; rg < 4; ++rg) {
        float v = prelu_m(acc3[nt][rg] + bias3[nt], al3);
        ft[(q * 4 + rg) * FSTR + nt * 16 + r] = f2bf(v);
      }
    s8v p0 = *(const s8v*)(ft + r * FSTR + q * 8);
    s8v p1 = *(const s8v*)(ft + r * FSTR + 32 + q * 8);

    f4v acc2[4];
#pragma unroll
    for (int nt = 0; nt < 4; ++nt) {
      f4v c = {0.f, 0.f, 0.f, 0.f};
      c = MFMA16(p0, ldfrag(pack, 40 + nt, lane), c);
      c = MFMA16(p1, ldfrag(pack, 44 + nt, lane), c);
      acc2[nt] = c;
    }

#pragma unroll
    for (int nt = 0; nt < 4; ++nt)
#pragma unroll
      for (int rg = 0; rg < 4; ++rg) {
        float v = prelu_m(acc2[nt][rg] + bias4[nt], alb);
        const int row = nbase + q * 4 + rg;
        zb[(size_t)row * 64 + nt * 16 + r] = f2bf(v);
        bs[nt] += v;
        bq[nt] += v * v;
      }
  }  // if (active)

  // ---- BN partials: block-level reduction, one atomic pass per block ------
#pragma unroll
  for (int nt = 0; nt < 4; ++nt) {
    float s = bs[nt];
    s += __shfl_xor(s, 16, 64);
    s += __shfl_xor(s, 32, 64);
    float ss = bq[nt];
    ss += __shfl_xor(ss, 16, 64);
    ss += __shfl_xor(ss, 32, 64);
    if (q == 0) {
      red[wv][nt * 16 + r]      = s;
      red[wv][64 + nt * 16 + r] = ss;
    }
  }
  __syncthreads();
  if (threadIdx.x < 128) {
    const int t = threadIdx.x;
    atomicAdd(&part[t], red[0][t] + red[1][t] + red[2][t] + red[3][t]);
  }
}

// ---------------------------------------------------------------------------
// BatchNorm finalize: grid-stride stream; reads z (bf16) + partials
// ---------------------------------------------------------------------------
__global__ __launch_bounds__(256) void bn_kernel(
    const unsigned short* __restrict__ zb,
    float* __restrict__ out,
    const float* __restrict__ part,
    const float* __restrict__ gamma,
    const float* __restrict__ beta)
{
  const size_t total = (size_t)NN * 16;   // quads of 4 elems
  const float inv_n = 1.0f / (float)NN;
  for (size_t i = (size_t)blockIdx.x * 256 + threadIdx.x; i < total;
       i += (size_t)gridDim.x * 256) {
    ushort4 v = ((const ushort4*)zb)[i];
    unsigned short e[4] = {v.x, v.y, v.z, v.w};
    float o[4];
    const int f0 = (int)((i * 4) & 63);
#pragma unroll
    for (int j = 0; j < 4; ++j) {
      const int f = f0 + j;
      const float mean = part[f] * inv_n;
      const float var  = part[64 + f] * inv_n - mean * mean;
      const float sc = rsqrtf(var + BN_EPS) * gamma[f];
      const float sh = beta[f] - mean * sc;
      o[j] = bf2f(e[j]) * sc + sh;
    }
    ((float4*)out)[i] = make_float4(o[0], o[1], o[2], o[3]);
  }
}

extern "C" void kernel_launch(void* const* d_in, const int* in_sizes, int n_in,
                              void* d_out, int out_size, void* d_ws, size_t ws_size,
                              hipStream_t stream) {
  const float* x  = (const float*)d_in[0];
  const int* ei   = (const int*)d_in[1];
  const float* W1 = (const float*)d_in[2];
  const float* b1 = (const float*)d_in[3];
  const float* a1 = (const float*)d_in[4];
  const float* W2 = (const float*)d_in[5];
  const float* b2 = (const float*)d_in[6];
  const float* a2 = (const float*)d_in[7];
  const float* W3 = (const float*)d_in[8];
  const float* b3 = (const float*)d_in[9];
  const float* a3 = (const float*)d_in[10];
  const float* W4 = (const float*)d_in[11];
  const float* b4 = (const float*)d_in[12];
  const float* ab = (const float*)d_in[13];
  const float* gm = (const float*)d_in[14];
  const float* bt = (const float*)d_in[15];

  float* part          = (float*)d_ws;                    // [128] f32 (+pad)
  unsigned short* F    = (unsigned short*)(part + 2048);  // [NN*64] bf16 (+b1)
  unsigned short* G    = F + (size_t)NN * 64;             // [NN*64] bf16
  unsigned short* XB   = G + (size_t)NN * 64;             // [NN*64] bf16
  unsigned short* zb   = XB + (size_t)NN * 64;            // [NN*64] bf16
  int* cursor          = (int*)(zb + (size_t)NN * 64);    // [CB*CPAD] padded
  int* fofs2           = cursor + (size_t)CB * CPAD;      // [CB*17] (+pad)
  int* ebufA           = fofs2 + CB * 17 + 8;             // [CB*SCAP]
  int* ebuf            = ebufA + (size_t)CB * SCAP;       // [CB*SCAP + 128]
  unsigned short* pack = (unsigned short*)(ebuf + (size_t)CB * SCAP + 128);
  float* out           = (float*)d_out;

  const int* srcp = ei;        // edge_index[0] = src (x_j)
  const int* dstp = ei + NE;   // edge_index[1] = dst (x_i)

  pack_kernel<<<dim3(1), dim3(256), 0, stream>>>(W1, W2, W3, W4, pack, part, cursor);
  pre_scatter_kernel<<<dim3(NBLKA + NPREB), dim3(256), 0, stream>>>(
      x, pack, b1, F, G, XB, srcp, dstp, cursor, ebufA);
  sort_b_kernel<<<dim3(CB), dim3(256), 0, stream>>>(ebufA, cursor, fofs2, ebuf);
  edge_agg_kernel<<<dim3((NBKT + 3) / 4), dim3(256), 0, stream>>>(
      F, G, ebuf, fofs2, pack, a1, b2, a2, XB, b3, a3, b4, ab, zb, part);
  bn_kernel<<<dim3(2048), dim3(256), 0, stream>>>(zb, out, part, gm, bt);
}